// Round 10
// baseline (1686.938 us; speedup 1.0000x reference)
//
#include <hip/hip_runtime.h>
#include <math.h>

// Problem constants (fixed by reference: B=2, N=2048, d_model=1024, H=16, D=64)
#define SEQ   2048
#define DM    1024
#define NTOK  4096      // B*SEQ
#define HEADS 16
#define HDIM  64
#define ROPE_SCALE 0.006135923151542565f   // 2*pi/1024
#define L2_10000   13.287712379549449f     // log2(10000)

typedef __attribute__((ext_vector_type(8)))  short bf16x8;
typedef __attribute__((ext_vector_type(4)))  unsigned short u16x4;
typedef __attribute__((ext_vector_type(4)))  float f32x4;

__device__ __forceinline__ unsigned short f2bf(float f) {
    unsigned int u = __float_as_uint(f);
    return (unsigned short)((u + 0x7FFFu + ((u >> 16) & 1u)) >> 16);
}
__device__ __forceinline__ float bf2f(unsigned short h) {
    return __uint_as_float(((unsigned int)h) << 16);
}

__device__ __forceinline__ void split8(const float* __restrict__ src, bf16x8& h, bf16x8& l) {
    float4 f0 = ((const float4*)src)[0];
    float4 f1 = ((const float4*)src)[1];
    float fv[8] = {f0.x,f0.y,f0.z,f0.w,f1.x,f1.y,f1.z,f1.w};
    #pragma unroll
    for (int j = 0; j < 8; ++j) {
        unsigned short hb = f2bf(fv[j]);
        h[j] = (short)hb;
        l[j] = (short)f2bf(fv[j] - bf2f(hb));
    }
}

__device__ __forceinline__ void gload16(const void* g, void* l) {
    __builtin_amdgcn_global_load_lds(
        (const __attribute__((address_space(1))) unsigned int*)g,
        (__attribute__((address_space(3))) unsigned int*)l, 16, 0, 0);
}

// ---------------------------------------------------------------------------
// Pack fp32 [R][1024] -> swizzled bf16 hi|lo tiles of 128 rows x 32 k.
// Tile (mt,kt) is 16384 B at (mt*32+kt)*8192 shorts. In-tile byte offset of
// (r,k,part p) = (r*128 + p*64 + k*2) ^ ((r&7)<<4).
// ---------------------------------------------------------------------------
__global__ __launch_bounds__(256) void pack_swz(
    const float* __restrict__ src, unsigned short* __restrict__ dst)
{
    const int idx = blockIdx.x*256 + threadIdx.x;   // one thread per 8 elements
    const int e = idx * 8;
    const int r = e >> 10, k0 = e & 1023;
    bf16x8 h, l;
    split8(src + (size_t)r*DM + k0, h, l);
    const int mt = r >> 7, rl = r & 127;
    const int kt = k0 >> 5, kl = k0 & 31;
    char* tb = (char*)(dst + ((size_t)(mt*32 + kt))*8192);
    const int sw = (rl & 7) << 4;
    *(bf16x8*)(tb + ((rl*128 + kl*2) ^ sw))      = h;
    *(bf16x8*)(tb + ((rl*128 + 64 + kl*2) ^ sw)) = l;
}

// Fused [Wq;Wk;Wv] variant: rows 0..3071, source row (r&1023) of W[r>>10].
__global__ __launch_bounds__(256) void pack_swz3(
    const float* __restrict__ Wq, const float* __restrict__ Wk,
    const float* __restrict__ Wv, unsigned short* __restrict__ dst)
{
    const int idx = blockIdx.x*256 + threadIdx.x;
    const int e = idx * 8;
    const int r = e >> 10, k0 = e & 1023;
    const int proj = r >> 10;
    const float* W = proj==0 ? Wq : (proj==1 ? Wk : Wv);
    bf16x8 h, l;
    split8(W + (size_t)(r & 1023)*DM + k0, h, l);
    const int mt = r >> 7, rl = r & 127;
    const int kt = k0 >> 5, kl = k0 & 31;
    char* tb = (char*)(dst + ((size_t)(mt*32 + kt))*8192);
    const int sw = (rl & 7) << 4;
    *(bf16x8*)(tb + ((rl*128 + kl*2) ^ sw))      = h;
    *(bf16x8*)(tb + ((rl*128 + 64 + kl*2) ^ sw)) = l;
}

// ---------------------------------------------------------------------------
// Split-bf16 MFMA GEMM, 256x128 block tile (2.6x fewer staged bytes/FLOP
// than 128x128), BK=32, 512 threads = 8 waves (4M x 2N), each wave 64x64 =
// 4x4 frags of 16x16, 3 MFMAs per product (hh+hl+lh). Single-buffered
// 48 KB LDS (A 32 KB = two stacked 128-row packed tiles, B 16 KB),
// 2 barriers per K-step, global_load_lds staging, XCD-chunked remap.
// mode 0: fused qkv (N=3072): bias + 2D RoPE; packed bf16 hi|lo out:
//   q,k -> [bh][plane][N][D] ; v -> TRANSPOSED [bh][plane][D][N].
// mode 1: out-proj (N=1024): bias, fp32 row-major [tok][1024].
// ---------------------------------------------------------------------------
__global__ __launch_bounds__(512, 6) void gemm_mfma(
    const unsigned short* __restrict__ Ap, const unsigned short* __restrict__ Bp,
    const int mode,
    const float* __restrict__ bq, const float* __restrict__ bk,
    const float* __restrict__ bv,
    const float* __restrict__ qpos, const float* __restrict__ kpos,
    unsigned short* __restrict__ qo, unsigned short* __restrict__ ko,
    unsigned short* __restrict__ vo,
    const float* __restrict__ bo, float* __restrict__ outp)
{
    __shared__ __align__(16) unsigned short Ab[16384];  // 32 KB (2 x hi|lo tile)
    __shared__ __align__(16) unsigned short Bb[8192];   // 16 KB

    const int tid = threadIdx.x, lane = tid & 63, wv = tid >> 6;
    const int col = lane & 15, grp = lane >> 4;
    const int wr = wv >> 1, wn = wv & 1;    // 4 x 2 wave grid

    // XCD-bijective remap (grid size divisible by 8)
    const int NX = gridDim.x, NB = NX * gridDim.y;
    const int bid = blockIdx.y * NX + blockIdx.x;
    const int bid2 = (bid & 7) * (NB >> 3) + (bid >> 3);
    const int nt = bid2 % NX, mt = bid2 / NX;

    f32x4 acc[4][4];
    #pragma unroll
    for (int mf=0; mf<4; ++mf)
        #pragma unroll
        for (int nf=0; nf<4; ++nf)
            acc[mf][nf] = (f32x4)0.f;

    for (int kt = 0; kt < 32; ++kt) {
        __syncthreads();     // previous step's readers done
        {   // stage 32 KB A (tiles mt*2, mt*2+1) + 16 KB B; LDS dest wave-uniform
            #pragma unroll
            for (int rep = 0; rep < 4; ++rep) {
                const int o = wv*4096 + rep*1024;            // 0..32767
                const int th = o >> 14, inner = o & 16383;
                const char* g = (const char*)Ap
                    + ((size_t)((mt*2 + th)*32 + kt))*16384 + inner;
                gload16(g + lane*16, (char*)Ab + o);
            }
            #pragma unroll
            for (int rep = 0; rep < 2; ++rep) {
                const int o = wv*2048 + rep*1024;            // 0..16383
                const char* g = (const char*)Bp
                    + ((size_t)(nt*32 + kt))*16384 + o;
                gload16(g + lane*16, (char*)Bb + o);
            }
        }
        __syncthreads();     // compiler drains vmcnt(0): tile ready
        const char* A = (const char*)Ab;
        const char* B = (const char*)Bb;
        bf16x8 ah[4], al[4];
        #pragma unroll
        for (int mf = 0; mf < 4; ++mf) {
            const int rl = wr*64 + mf*16 + col;              // 0..255
            const int th = rl >> 7, r7 = rl & 127;
            const int b0 = r7*128 + grp*16;
            const int sw = (r7 & 7) << 4;
            ah[mf] = *(const bf16x8*)(A + th*16384 + (b0 ^ sw));
            al[mf] = *(const bf16x8*)(A + th*16384 + ((b0 + 64) ^ sw));
        }
        #pragma unroll
        for (int nf = 0; nf < 4; ++nf) {
            const int rl = wn*64 + nf*16 + col;
            const int b0 = rl*128 + grp*16;
            const int sw = (rl & 7) << 4;
            bf16x8 bh  = *(const bf16x8*)(B + (b0 ^ sw));
            bf16x8 blo = *(const bf16x8*)(B + ((b0 + 64) ^ sw));
            #pragma unroll
            for (int mf = 0; mf < 4; ++mf) {
                acc[mf][nf] = __builtin_amdgcn_mfma_f32_16x16x32_bf16(ah[mf], bh,  acc[mf][nf], 0,0,0);
                acc[mf][nf] = __builtin_amdgcn_mfma_f32_16x16x32_bf16(ah[mf], blo, acc[mf][nf], 0,0,0);
                acc[mf][nf] = __builtin_amdgcn_mfma_f32_16x16x32_bf16(al[mf], bh,  acc[mf][nf], 0,0,0);
            }
        }
    }

    // ---- epilogue. C row = m0+wr*64+mf*16+grp*4+i ; C col = n0+wn*64+nf*16+col
    const int m0 = mt*256, n0 = nt*128;
    if (mode == 1) {
        #pragma unroll
        for (int nf = 0; nf < 4; ++nf) {
            const int n = n0 + wn*64 + nf*16 + col;
            const float bn = bo[n];
            #pragma unroll
            for (int mf = 0; mf < 4; ++mf)
                #pragma unroll
                for (int i = 0; i < 4; ++i) {
                    const int tok = m0 + wr*64 + mf*16 + grp*4 + i;
                    outp[(size_t)tok*DM + n] = acc[mf][nf][i] + bn;
                }
        }
    } else {
        const int proj = n0 >> 10;              // whole block is one projection
        const float* bb = proj==0 ? bq : (proj==1 ? bk : bv);
        unsigned short* op = proj==0 ? qo : (proj==1 ? ko : vo);
        const float* pp = proj==0 ? qpos : kpos;
        #pragma unroll
        for (int nf = 0; nf < 4; ++nf) {
            const int n  = n0 + wn*64 + nf*16 + col;
            const int nn = n & 1023;
            const int h  = nn >> 6, dd = nn & 63;
            const float bn = bb[nn];
            if (proj == 2) {
                // v: packed transposed [bh][pl][D][N]; 4 consecutive sq -> u16x4
                #pragma unroll
                for (int mf = 0; mf < 4; ++mf) {
                    const int tok0 = m0 + wr*64 + mf*16 + grp*4;
                    const int b = tok0 >> 11, sq0 = tok0 & 2047;
                    u16x4 h4, l4;
                    #pragma unroll
                    for (int i = 0; i < 4; ++i) {
                        const float val = acc[mf][nf][i] + bn;
                        unsigned short hb = f2bf(val);
                        h4[i] = hb;
                        l4[i] = f2bf(val - bf2f(hb));
                    }
                    const int bh2 = (b*HEADS + h)*2;
                    *(u16x4*)(op + ((size_t)(bh2+0)*HDIM + dd)*SEQ + sq0) = h4;
                    *(u16x4*)(op + ((size_t)(bh2+1)*HDIM + dd)*SEQ + sq0) = l4;
                }
            } else {
                // q,k: RoPE then packed [bh][pl][N][D]
                const int plane = dd >> 5;
                const float e = (float)(dd & 30) * (1.0f/32.0f);
                const float invf = exp2f(-L2_10000 * e);
                #pragma unroll
                for (int mf = 0; mf < 4; ++mf)
                    #pragma unroll
                    for (int i = 0; i < 4; ++i) {
                        const int tok = m0 + wr*64 + mf*16 + grp*4 + i;
                        const int b = tok >> 11, sq = tok & 2047;
                        const float pv = pp[((size_t)(b*SEQ + sq))*2 + plane];
                        const float ang = pv * ROPE_SCALE * invf;
                        float s, c;
                        sincosf(ang, &s, &c);
                        const float val = acc[mf][nf][i] + bn;
                        const float prt = __shfl_xor(val, 1);
                        const float res = (dd & 1) ? (prt*s + val*c) : (val*c - prt*s);
                        unsigned short hb = f2bf(res);
                        unsigned short lb = f2bf(res - bf2f(hb));
                        const int bh2 = (b*HEADS + h)*2;
                        op[((size_t)(bh2+0)*SEQ + sq)*HDIM + dd] = hb;
                        op[((size_t)(bh2+1)*SEQ + sq)*HDIM + dd] = lb;
                    }
            }
        }
    }
}

// ---------------------------------------------------------------------------
// MFMA flash attention reading PRE-SPLIT packed bf16 hi|lo q/k/v (unchanged).
// q,k: [bh][pl][N][D]; v: [bh][pl][D][N] (pre-transposed).
// ---------------------------------------------------------------------------
#define KB 32

__global__ __launch_bounds__(256) void attn_mfma(
    const unsigned short* __restrict__ q, const unsigned short* __restrict__ k,
    const unsigned short* __restrict__ v, float* __restrict__ ao)
{
    const int bh  = blockIdx.y;
    const int qb0 = blockIdx.x * 128;
    const int tid = threadIdx.x;
    const int lane = tid & 63;
    const int wv   = tid >> 6;
    const int col  = lane & 15;
    const int grp  = lane >> 4;

    __shared__ __align__(16) unsigned short Khi[KB][72];
    __shared__ __align__(16) unsigned short Klo[KB][72];
    __shared__ __align__(16) unsigned short Vthi[HDIM][40];
    __shared__ __align__(16) unsigned short Vtlo[HDIM][40];
    __shared__ __align__(16) unsigned short Pb[4][32][40];

    const unsigned short* kh_g = k + (size_t)(bh*2)*SEQ*HDIM;
    const unsigned short* kl_g = kh_g + (size_t)SEQ*HDIM;
    const unsigned short* vh_g = v + (size_t)(bh*2)*HDIM*SEQ;
    const unsigned short* vl_g = vh_g + (size_t)HDIM*SEQ;

    bf16x8 qhi[2][2], qlo[2][2];
    {
        const unsigned short* qh_g = q + (size_t)(bh*2)*SEQ*HDIM;
        const unsigned short* ql_g = qh_g + (size_t)SEQ*HDIM;
        #pragma unroll
        for (int mf = 0; mf < 2; ++mf)
            #pragma unroll
            for (int ks = 0; ks < 2; ++ks) {
                const size_t off = (size_t)(qb0 + wv*32 + mf*16 + col)*HDIM + ks*32 + grp*8;
                qhi[mf][ks] = *(const bf16x8*)(qh_g + off);
                qlo[mf][ks] = *(const bf16x8*)(ql_g + off);
            }
    }

    f32x4 o[2][4];
    #pragma unroll
    for (int mf=0; mf<2; ++mf)
        #pragma unroll
        for (int nf=0; nf<4; ++nf)
            o[mf][nf] = (f32x4)0.f;
    float mrun[2][4], lrun[2][4];
    #pragma unroll
    for (int mf=0; mf<2; ++mf)
        #pragma unroll
        for (int r=0; r<4; ++r) { mrun[mf][r] = -INFINITY; lrun[mf][r] = 0.f; }

    for (int kt = 0; kt < SEQ; kt += KB) {
        __syncthreads();
        {   // K tile: pure copy
            const int row = tid >> 3, c0 = (tid & 7) * 8;
            const size_t off = (size_t)(kt + row)*HDIM + c0;
            *(bf16x8*)&Khi[row][c0] = *(const bf16x8*)(kh_g + off);
            *(bf16x8*)&Klo[row][c0] = *(const bf16x8*)(kl_g + off);
        }
        {   // V^T tile: pure copy
            const int d = tid >> 2, c = (tid & 3) * 8;
            const size_t off = (size_t)d*SEQ + kt + c;
            *(bf16x8*)&Vthi[d][c] = *(const bf16x8*)(vh_g + off);
            *(bf16x8*)&Vtlo[d][c] = *(const bf16x8*)(vl_g + off);
        }
        __syncthreads();

        f32x4 s[2][2];
        #pragma unroll
        for (int mf=0; mf<2; ++mf)
            #pragma unroll
            for (int nf=0; nf<2; ++nf)
                s[mf][nf] = (f32x4)0.f;
        #pragma unroll
        for (int ks = 0; ks < 2; ++ks) {
            bf16x8 kh[2], kl[2];
            #pragma unroll
            for (int nf = 0; nf < 2; ++nf) {
                kh[nf] = *(const bf16x8*)&Khi[nf*16 + col][ks*32 + grp*8];
                kl[nf] = *(const bf16x8*)&Klo[nf*16 + col][ks*32 + grp*8];
            }
            #pragma unroll
            for (int mf = 0; mf < 2; ++mf)
                #pragma unroll
                for (int nf = 0; nf < 2; ++nf) {
                    s[mf][nf] = __builtin_amdgcn_mfma_f32_16x16x32_bf16(qhi[mf][ks], kh[nf], s[mf][nf], 0,0,0);
                    s[mf][nf] = __builtin_amdgcn_mfma_f32_16x16x32_bf16(qlo[mf][ks], kh[nf], s[mf][nf], 0,0,0);
                    s[mf][nf] = __builtin_amdgcn_mfma_f32_16x16x32_bf16(qhi[mf][ks], kl[nf], s[mf][nf], 0,0,0);
                }
        }

        #pragma unroll
        for (int mf=0; mf<2; ++mf)
            #pragma unroll
            for (int nf=0; nf<2; ++nf)
                s[mf][nf] *= 0.125f;

        #pragma unroll
        for (int mf = 0; mf < 2; ++mf) {
            #pragma unroll
            for (int r = 0; r < 4; ++r) {
                float m2 = fmaxf(s[mf][0][r], s[mf][1][r]);
                m2 = fmaxf(m2, __shfl_xor(m2, 1, 16));
                m2 = fmaxf(m2, __shfl_xor(m2, 2, 16));
                m2 = fmaxf(m2, __shfl_xor(m2, 4, 16));
                m2 = fmaxf(m2, __shfl_xor(m2, 8, 16));
                const float mnew = fmaxf(mrun[mf][r], m2);
                const float corr = __expf(mrun[mf][r] - mnew);
                mrun[mf][r] = mnew;
                const float p0 = __expf(s[mf][0][r] - mnew);
                const float p1 = __expf(s[mf][1][r] - mnew);
                float ts = p0 + p1;
                ts += __shfl_xor(ts, 1, 16);
                ts += __shfl_xor(ts, 2, 16);
                ts += __shfl_xor(ts, 4, 16);
                ts += __shfl_xor(ts, 8, 16);
                lrun[mf][r] = lrun[mf][r]*corr + ts;
                #pragma unroll
                for (int nf=0; nf<4; ++nf) o[mf][nf][r] *= corr;
                Pb[wv][mf*16 + grp*4 + r][col]      = f2bf(p0);
                Pb[wv][mf*16 + grp*4 + r][16 + col] = f2bf(p1);
            }
        }

        bf16x8 pa[2];
        #pragma unroll
        for (int mf=0; mf<2; ++mf)
            pa[mf] = *(const bf16x8*)&Pb[wv][mf*16 + col][grp*8];
        #pragma unroll
        for (int nf = 0; nf < 4; ++nf) {
            bf16x8 vh = *(const bf16x8*)&Vthi[nf*16 + col][grp*8];
            bf16x8 vl = *(const bf16x8*)&Vtlo[nf*16 + col][grp*8];
            #pragma unroll
            for (int mf = 0; mf < 2; ++mf) {
                o[mf][nf] = __builtin_amdgcn_mfma_f32_16x16x32_bf16(pa[mf], vh, o[mf][nf], 0,0,0);
                o[mf][nf] = __builtin_amdgcn_mfma_f32_16x16x32_bf16(pa[mf], vl, o[mf][nf], 0,0,0);
            }
        }
    }

    const int b = bh >> 4, h = bh & 15;
    #pragma unroll
    for (int mf = 0; mf < 2; ++mf)
        #pragma unroll
        for (int r = 0; r < 4; ++r) {
            const float inv = 1.0f / lrun[mf][r];
            const int n = qb0 + wv*32 + mf*16 + grp*4 + r;
            float* orow = ao + (((size_t)b*SEQ + n)*HEADS + h)*HDIM;
            #pragma unroll
            for (int nf = 0; nf < 4; ++nf)
                orow[nf*16 + col] = o[mf][nf][r] * inv;
        }
}

// ---------------------------------------------------------------------------
extern "C" void kernel_launch(void* const* d_in, const int* in_sizes, int n_in,
                              void* d_out, int out_size, void* d_ws, size_t ws_size,
                              hipStream_t stream)
{
    const float* x    = (const float*)d_in[0];
    const float* qpos = (const float*)d_in[1];
    const float* kpos = (const float*)d_in[2];
    const float* Wq   = (const float*)d_in[3];
    const float* bq   = (const float*)d_in[4];
    const float* Wk   = (const float*)d_in[5];
    const float* bk   = (const float*)d_in[6];
    const float* Wv   = (const float*)d_in[7];
    const float* bv   = (const float*)d_in[8];
    const float* Wo   = (const float*)d_in[9];
    const float* bo   = (const float*)d_in[10];
    float* out = (float*)d_out;

    // workspace (80 MB), with overlays:
    //   qp 16 MB | kp 16 MB | vp 16 MB | X/aw 16 MB | Wqkvp 12 MB + Wop 4 MB
    unsigned short* qp = (unsigned short*)d_ws;                  // 8M ushorts
    unsigned short* kp = qp + (size_t)8388608;
    unsigned short* vp = kp + (size_t)8388608;
    unsigned short* Xp = vp + (size_t)8388608;                   // packed x
    float*          aw = (float*)Xp;                             // overlay
    unsigned short* Wqkvp = Xp + (size_t)8388608;
    unsigned short* Wop   = Wqkvp + (size_t)6291456;
    unsigned short* Ap2   = qp;                                  // overlay

    pack_swz <<<2048, 256, 0, stream>>>(x, Xp);
    pack_swz3<<<1536, 256, 0, stream>>>(Wq, Wk, Wv, Wqkvp);
    pack_swz <<< 512, 256, 0, stream>>>(Wo, Wop);

    gemm_mfma<<<dim3(24, 16), 512, 0, stream>>>(
        Xp, Wqkvp, 0, bq, bk, bv, qpos, kpos, qp, kp, vp, nullptr, nullptr);

    attn_mfma<<<dim3(SEQ/128, 2*HEADS), 256, 0, stream>>>(qp, kp, vp, aw);

    pack_swz <<<2048, 256, 0, stream>>>(aw, Ap2);

    gemm_mfma<<<dim3(8, 16), 512, 0, stream>>>(
        Ap2, Wop, 1, nullptr, nullptr, nullptr, nullptr, nullptr,
        nullptr, nullptr, nullptr, bo, out);
}

// Round 11
// 775.260 us; speedup vs baseline: 2.1760x; 2.1760x over previous
//
#include <hip/hip_runtime.h>
#include <math.h>

// Problem constants (fixed by reference: B=2, N=2048, d_model=1024, H=16, D=64)
#define SEQ   2048
#define DM    1024
#define NTOK  4096      // B*SEQ
#define HEADS 16
#define HDIM  64
#define ROPE_SCALE 0.006135923151542565f   // 2*pi/1024
#define L2_10000   13.287712379549449f     // log2(10000)

typedef __attribute__((ext_vector_type(8)))  short bf16x8;
typedef __attribute__((ext_vector_type(4)))  unsigned short u16x4;
typedef __attribute__((ext_vector_type(4)))  float f32x4;

__device__ __forceinline__ unsigned short f2bf(float f) {
    unsigned int u = __float_as_uint(f);
    return (unsigned short)((u + 0x7FFFu + ((u >> 16) & 1u)) >> 16);
}
__device__ __forceinline__ float bf2f(unsigned short h) {
    return __uint_as_float(((unsigned int)h) << 16);
}

__device__ __forceinline__ void split8(const float* __restrict__ src, bf16x8& h, bf16x8& l) {
    float4 f0 = ((const float4*)src)[0];
    float4 f1 = ((const float4*)src)[1];
    float fv[8] = {f0.x,f0.y,f0.z,f0.w,f1.x,f1.y,f1.z,f1.w};
    #pragma unroll
    for (int j = 0; j < 8; ++j) {
        unsigned short hb = f2bf(fv[j]);
        h[j] = (short)hb;
        l[j] = (short)f2bf(fv[j] - bf2f(hb));
    }
}

__device__ __forceinline__ void gload16(const void* g, void* l) {
    __builtin_amdgcn_global_load_lds(
        (const __attribute__((address_space(1))) unsigned int*)g,
        (__attribute__((address_space(3))) unsigned int*)l, 16, 0, 0);
}

// ---------------------------------------------------------------------------
// Pack fp32 [R][1024] -> swizzled bf16 hi|lo tiles of 128 rows x 32 k.
// Tile (mt,kt) is 16384 B at (mt*32+kt)*8192 shorts. In-tile byte offset of
// (r,k,part p) = (r*128 + p*64 + k*2) ^ ((r&7)<<4).
// ---------------------------------------------------------------------------
__global__ __launch_bounds__(256) void pack_swz(
    const float* __restrict__ src, unsigned short* __restrict__ dst)
{
    const int idx = blockIdx.x*256 + threadIdx.x;   // one thread per 8 elements
    const int e = idx * 8;
    const int r = e >> 10, k0 = e & 1023;
    bf16x8 h, l;
    split8(src + (size_t)r*DM + k0, h, l);
    const int mt = r >> 7, rl = r & 127;
    const int kt = k0 >> 5, kl = k0 & 31;
    char* tb = (char*)(dst + ((size_t)(mt*32 + kt))*8192);
    const int sw = (rl & 7) << 4;
    *(bf16x8*)(tb + ((rl*128 + kl*2) ^ sw))      = h;
    *(bf16x8*)(tb + ((rl*128 + 64 + kl*2) ^ sw)) = l;
}

// Fused [Wq;Wk;Wv] variant: rows 0..3071, source row (r&1023) of W[r>>10].
__global__ __launch_bounds__(256) void pack_swz3(
    const float* __restrict__ Wq, const float* __restrict__ Wk,
    const float* __restrict__ Wv, unsigned short* __restrict__ dst)
{
    const int idx = blockIdx.x*256 + threadIdx.x;
    const int e = idx * 8;
    const int r = e >> 10, k0 = e & 1023;
    const int proj = r >> 10;
    const float* W = proj==0 ? Wq : (proj==1 ? Wk : Wv);
    bf16x8 h, l;
    split8(W + (size_t)(r & 1023)*DM + k0, h, l);
    const int mt = r >> 7, rl = r & 127;
    const int kt = k0 >> 5, kl = k0 & 31;
    char* tb = (char*)(dst + ((size_t)(mt*32 + kt))*8192);
    const int sw = (rl & 7) << 4;
    *(bf16x8*)(tb + ((rl*128 + kl*2) ^ sw))      = h;
    *(bf16x8*)(tb + ((rl*128 + 64 + kl*2) ^ sw)) = l;
}

// ---------------------------------------------------------------------------
// Split-bf16 MFMA GEMM, 256x128 block tile, BK=32, 512 threads = 8 waves
// (4M x 2N), each wave 64x64 = 4x4 frags of 16x16, 3 MFMAs per product
// (hh+hl+lh). Single-buffered 48 KB LDS (A 32 KB = two stacked 128-row
// packed tiles, B 16 KB), 2 barriers per K-step, global_load_lds staging,
// XCD-chunked remap. NOTE: no min-waves clause in launch_bounds — r10's
// (512,6) capped VGPR to 40 and spilled the accumulator (scratch traffic
// 4.4 GB). LDS alone bounds occupancy at 3 blocks/CU here.
// mode 0: fused qkv (N=3072): bias + 2D RoPE; packed bf16 hi|lo out:
//   q,k -> [bh][plane][N][D] ; v -> TRANSPOSED [bh][plane][D][N].
// mode 1: out-proj (N=1024): bias, fp32 row-major [tok][1024].
// ---------------------------------------------------------------------------
__global__ __launch_bounds__(512) void gemm_mfma(
    const unsigned short* __restrict__ Ap, const unsigned short* __restrict__ Bp,
    const int mode,
    const float* __restrict__ bq, const float* __restrict__ bk,
    const float* __restrict__ bv,
    const float* __restrict__ qpos, const float* __restrict__ kpos,
    unsigned short* __restrict__ qo, unsigned short* __restrict__ ko,
    unsigned short* __restrict__ vo,
    const float* __restrict__ bo, float* __restrict__ outp)
{
    __shared__ __align__(16) unsigned short Ab[16384];  // 32 KB (2 x hi|lo tile)
    __shared__ __align__(16) unsigned short Bb[8192];   // 16 KB

    const int tid = threadIdx.x, lane = tid & 63, wv = tid >> 6;
    const int col = lane & 15, grp = lane >> 4;
    const int wr = wv >> 1, wn = wv & 1;    // 4 x 2 wave grid

    // XCD-bijective remap (grid size divisible by 8)
    const int NX = gridDim.x, NB = NX * gridDim.y;
    const int bid = blockIdx.y * NX + blockIdx.x;
    const int bid2 = (bid & 7) * (NB >> 3) + (bid >> 3);
    const int nt = bid2 % NX, mt = bid2 / NX;

    f32x4 acc[4][4];
    #pragma unroll
    for (int mf=0; mf<4; ++mf)
        #pragma unroll
        for (int nf=0; nf<4; ++nf)
            acc[mf][nf] = (f32x4)0.f;

    for (int kt = 0; kt < 32; ++kt) {
        __syncthreads();     // previous step's readers done
        {   // stage 32 KB A (tiles mt*2, mt*2+1) + 16 KB B; LDS dest wave-uniform
            #pragma unroll
            for (int rep = 0; rep < 4; ++rep) {
                const int o = wv*4096 + rep*1024;            // 0..32767
                const int th = o >> 14, inner = o & 16383;
                const char* g = (const char*)Ap
                    + ((size_t)((mt*2 + th)*32 + kt))*16384 + inner;
                gload16(g + lane*16, (char*)Ab + o);
            }
            #pragma unroll
            for (int rep = 0; rep < 2; ++rep) {
                const int o = wv*2048 + rep*1024;            // 0..16383
                const char* g = (const char*)Bp
                    + ((size_t)(nt*32 + kt))*16384 + o;
                gload16(g + lane*16, (char*)Bb + o);
            }
        }
        __syncthreads();     // compiler drains vmcnt(0): tile ready
        const char* A = (const char*)Ab;
        const char* B = (const char*)Bb;
        bf16x8 ah[4], al[4];
        #pragma unroll
        for (int mf = 0; mf < 4; ++mf) {
            const int rl = wr*64 + mf*16 + col;              // 0..255
            const int th = rl >> 7, r7 = rl & 127;
            const int b0 = r7*128 + grp*16;
            const int sw = (r7 & 7) << 4;
            ah[mf] = *(const bf16x8*)(A + th*16384 + (b0 ^ sw));
            al[mf] = *(const bf16x8*)(A + th*16384 + ((b0 + 64) ^ sw));
        }
        #pragma unroll
        for (int nf = 0; nf < 4; ++nf) {
            const int rl = wn*64 + nf*16 + col;
            const int b0 = rl*128 + grp*16;
            const int sw = (rl & 7) << 4;
            bf16x8 bh  = *(const bf16x8*)(B + (b0 ^ sw));
            bf16x8 blo = *(const bf16x8*)(B + ((b0 + 64) ^ sw));
            #pragma unroll
            for (int mf = 0; mf < 4; ++mf) {
                acc[mf][nf] = __builtin_amdgcn_mfma_f32_16x16x32_bf16(ah[mf], bh,  acc[mf][nf], 0,0,0);
                acc[mf][nf] = __builtin_amdgcn_mfma_f32_16x16x32_bf16(ah[mf], blo, acc[mf][nf], 0,0,0);
                acc[mf][nf] = __builtin_amdgcn_mfma_f32_16x16x32_bf16(al[mf], bh,  acc[mf][nf], 0,0,0);
            }
        }
    }

    // ---- epilogue. C row = m0+wr*64+mf*16+grp*4+i ; C col = n0+wn*64+nf*16+col
    const int m0 = mt*256, n0 = nt*128;
    if (mode == 1) {
        #pragma unroll
        for (int nf = 0; nf < 4; ++nf) {
            const int n = n0 + wn*64 + nf*16 + col;
            const float bn = bo[n];
            #pragma unroll
            for (int mf = 0; mf < 4; ++mf)
                #pragma unroll
                for (int i = 0; i < 4; ++i) {
                    const int tok = m0 + wr*64 + mf*16 + grp*4 + i;
                    outp[(size_t)tok*DM + n] = acc[mf][nf][i] + bn;
                }
        }
    } else {
        const int proj = n0 >> 10;              // whole block is one projection
        const float* bb = proj==0 ? bq : (proj==1 ? bk : bv);
        unsigned short* op = proj==0 ? qo : (proj==1 ? ko : vo);
        const float* pp = proj==0 ? qpos : kpos;
        #pragma unroll
        for (int nf = 0; nf < 4; ++nf) {
            const int n  = n0 + wn*64 + nf*16 + col;
            const int nn = n & 1023;
            const int h  = nn >> 6, dd = nn & 63;
            const float bn = bb[nn];
            if (proj == 2) {
                // v: packed transposed [bh][pl][D][N]; 4 consecutive sq -> u16x4
                #pragma unroll
                for (int mf = 0; mf < 4; ++mf) {
                    const int tok0 = m0 + wr*64 + mf*16 + grp*4;
                    const int b = tok0 >> 11, sq0 = tok0 & 2047;
                    u16x4 h4, l4;
                    #pragma unroll
                    for (int i = 0; i < 4; ++i) {
                        const float val = acc[mf][nf][i] + bn;
                        unsigned short hb = f2bf(val);
                        h4[i] = hb;
                        l4[i] = f2bf(val - bf2f(hb));
                    }
                    const int bh2 = (b*HEADS + h)*2;
                    *(u16x4*)(op + ((size_t)(bh2+0)*HDIM + dd)*SEQ + sq0) = h4;
                    *(u16x4*)(op + ((size_t)(bh2+1)*HDIM + dd)*SEQ + sq0) = l4;
                }
            } else {
                // q,k: RoPE then packed [bh][pl][N][D]
                const int plane = dd >> 5;
                const float e = (float)(dd & 30) * (1.0f/32.0f);
                const float invf = exp2f(-L2_10000 * e);
                #pragma unroll
                for (int mf = 0; mf < 4; ++mf)
                    #pragma unroll
                    for (int i = 0; i < 4; ++i) {
                        const int tok = m0 + wr*64 + mf*16 + grp*4 + i;
                        const int b = tok >> 11, sq = tok & 2047;
                        const float pv = pp[((size_t)(b*SEQ + sq))*2 + plane];
                        const float ang = pv * ROPE_SCALE * invf;
                        float s, c;
                        sincosf(ang, &s, &c);
                        const float val = acc[mf][nf][i] + bn;
                        const float prt = __shfl_xor(val, 1);
                        const float res = (dd & 1) ? (prt*s + val*c) : (val*c - prt*s);
                        unsigned short hb = f2bf(res);
                        unsigned short lb = f2bf(res - bf2f(hb));
                        const int bh2 = (b*HEADS + h)*2;
                        op[((size_t)(bh2+0)*SEQ + sq)*HDIM + dd] = hb;
                        op[((size_t)(bh2+1)*SEQ + sq)*HDIM + dd] = lb;
                    }
            }
        }
    }
}

// ---------------------------------------------------------------------------
// MFMA flash attention reading PRE-SPLIT packed bf16 hi|lo q/k/v (unchanged).
// q,k: [bh][pl][N][D]; v: [bh][pl][D][N] (pre-transposed).
// ---------------------------------------------------------------------------
#define KB 32

__global__ __launch_bounds__(256) void attn_mfma(
    const unsigned short* __restrict__ q, const unsigned short* __restrict__ k,
    const unsigned short* __restrict__ v, float* __restrict__ ao)
{
    const int bh  = blockIdx.y;
    const int qb0 = blockIdx.x * 128;
    const int tid = threadIdx.x;
    const int lane = tid & 63;
    const int wv   = tid >> 6;
    const int col  = lane & 15;
    const int grp  = lane >> 4;

    __shared__ __align__(16) unsigned short Khi[KB][72];
    __shared__ __align__(16) unsigned short Klo[KB][72];
    __shared__ __align__(16) unsigned short Vthi[HDIM][40];
    __shared__ __align__(16) unsigned short Vtlo[HDIM][40];
    __shared__ __align__(16) unsigned short Pb[4][32][40];

    const unsigned short* kh_g = k + (size_t)(bh*2)*SEQ*HDIM;
    const unsigned short* kl_g = kh_g + (size_t)SEQ*HDIM;
    const unsigned short* vh_g = v + (size_t)(bh*2)*HDIM*SEQ;
    const unsigned short* vl_g = vh_g + (size_t)HDIM*SEQ;

    bf16x8 qhi[2][2], qlo[2][2];
    {
        const unsigned short* qh_g = q + (size_t)(bh*2)*SEQ*HDIM;
        const unsigned short* ql_g = qh_g + (size_t)SEQ*HDIM;
        #pragma unroll
        for (int mf = 0; mf < 2; ++mf)
            #pragma unroll
            for (int ks = 0; ks < 2; ++ks) {
                const size_t off = (size_t)(qb0 + wv*32 + mf*16 + col)*HDIM + ks*32 + grp*8;
                qhi[mf][ks] = *(const bf16x8*)(qh_g + off);
                qlo[mf][ks] = *(const bf16x8*)(ql_g + off);
            }
    }

    f32x4 o[2][4];
    #pragma unroll
    for (int mf=0; mf<2; ++mf)
        #pragma unroll
        for (int nf=0; nf<4; ++nf)
            o[mf][nf] = (f32x4)0.f;
    float mrun[2][4], lrun[2][4];
    #pragma unroll
    for (int mf=0; mf<2; ++mf)
        #pragma unroll
        for (int r=0; r<4; ++r) { mrun[mf][r] = -INFINITY; lrun[mf][r] = 0.f; }

    for (int kt = 0; kt < SEQ; kt += KB) {
        __syncthreads();
        {   // K tile: pure copy
            const int row = tid >> 3, c0 = (tid & 7) * 8;
            const size_t off = (size_t)(kt + row)*HDIM + c0;
            *(bf16x8*)&Khi[row][c0] = *(const bf16x8*)(kh_g + off);
            *(bf16x8*)&Klo[row][c0] = *(const bf16x8*)(kl_g + off);
        }
        {   // V^T tile: pure copy
            const int d = tid >> 2, c = (tid & 3) * 8;
            const size_t off = (size_t)d*SEQ + kt + c;
            *(bf16x8*)&Vthi[d][c] = *(const bf16x8*)(vh_g + off);
            *(bf16x8*)&Vtlo[d][c] = *(const bf16x8*)(vl_g + off);
        }
        __syncthreads();

        f32x4 s[2][2];
        #pragma unroll
        for (int mf=0; mf<2; ++mf)
            #pragma unroll
            for (int nf=0; nf<2; ++nf)
                s[mf][nf] = (f32x4)0.f;
        #pragma unroll
        for (int ks = 0; ks < 2; ++ks) {
            bf16x8 kh[2], kl[2];
            #pragma unroll
            for (int nf = 0; nf < 2; ++nf) {
                kh[nf] = *(const bf16x8*)&Khi[nf*16 + col][ks*32 + grp*8];
                kl[nf] = *(const bf16x8*)&Klo[nf*16 + col][ks*32 + grp*8];
            }
            #pragma unroll
            for (int mf = 0; mf < 2; ++mf)
                #pragma unroll
                for (int nf = 0; nf < 2; ++nf) {
                    s[mf][nf] = __builtin_amdgcn_mfma_f32_16x16x32_bf16(qhi[mf][ks], kh[nf], s[mf][nf], 0,0,0);
                    s[mf][nf] = __builtin_amdgcn_mfma_f32_16x16x32_bf16(qlo[mf][ks], kh[nf], s[mf][nf], 0,0,0);
                    s[mf][nf] = __builtin_amdgcn_mfma_f32_16x16x32_bf16(qhi[mf][ks], kl[nf], s[mf][nf], 0,0,0);
                }
        }

        #pragma unroll
        for (int mf=0; mf<2; ++mf)
            #pragma unroll
            for (int nf=0; nf<2; ++nf)
                s[mf][nf] *= 0.125f;

        #pragma unroll
        for (int mf = 0; mf < 2; ++mf) {
            #pragma unroll
            for (int r = 0; r < 4; ++r) {
                float m2 = fmaxf(s[mf][0][r], s[mf][1][r]);
                m2 = fmaxf(m2, __shfl_xor(m2, 1, 16));
                m2 = fmaxf(m2, __shfl_xor(m2, 2, 16));
                m2 = fmaxf(m2, __shfl_xor(m2, 4, 16));
                m2 = fmaxf(m2, __shfl_xor(m2, 8, 16));
                const float mnew = fmaxf(mrun[mf][r], m2);
                const float corr = __expf(mrun[mf][r] - mnew);
                mrun[mf][r] = mnew;
                const float p0 = __expf(s[mf][0][r] - mnew);
                const float p1 = __expf(s[mf][1][r] - mnew);
                float ts = p0 + p1;
                ts += __shfl_xor(ts, 1, 16);
                ts += __shfl_xor(ts, 2, 16);
                ts += __shfl_xor(ts, 4, 16);
                ts += __shfl_xor(ts, 8, 16);
                lrun[mf][r] = lrun[mf][r]*corr + ts;
                #pragma unroll
                for (int nf=0; nf<4; ++nf) o[mf][nf][r] *= corr;
                Pb[wv][mf*16 + grp*4 + r][col]      = f2bf(p0);
                Pb[wv][mf*16 + grp*4 + r][16 + col] = f2bf(p1);
            }
        }

        bf16x8 pa[2];
        #pragma unroll
        for (int mf=0; mf<2; ++mf)
            pa[mf] = *(const bf16x8*)&Pb[wv][mf*16 + col][grp*8];
        #pragma unroll
        for (int nf = 0; nf < 4; ++nf) {
            bf16x8 vh = *(const bf16x8*)&Vthi[nf*16 + col][grp*8];
            bf16x8 vl = *(const bf16x8*)&Vtlo[nf*16 + col][grp*8];
            #pragma unroll
            for (int mf = 0; mf < 2; ++mf) {
                o[mf][nf] = __builtin_amdgcn_mfma_f32_16x16x32_bf16(pa[mf], vh, o[mf][nf], 0,0,0);
                o[mf][nf] = __builtin_amdgcn_mfma_f32_16x16x32_bf16(pa[mf], vl, o[mf][nf], 0,0,0);
            }
        }
    }

    const int b = bh >> 4, h = bh & 15;
    #pragma unroll
    for (int mf = 0; mf < 2; ++mf)
        #pragma unroll
        for (int r = 0; r < 4; ++r) {
            const float inv = 1.0f / lrun[mf][r];
            const int n = qb0 + wv*32 + mf*16 + grp*4 + r;
            float* orow = ao + (((size_t)b*SEQ + n)*HEADS + h)*HDIM;
            #pragma unroll
            for (int nf = 0; nf < 4; ++nf)
                orow[nf*16 + col] = o[mf][nf][r] * inv;
        }
}

// ---------------------------------------------------------------------------
extern "C" void kernel_launch(void* const* d_in, const int* in_sizes, int n_in,
                              void* d_out, int out_size, void* d_ws, size_t ws_size,
                              hipStream_t stream)
{
    const float* x    = (const float*)d_in[0];
    const float* qpos = (const float*)d_in[1];
    const float* kpos = (const float*)d_in[2];
    const float* Wq   = (const float*)d_in[3];
    const float* bq   = (const float*)d_in[4];
    const float* Wk   = (const float*)d_in[5];
    const float* bk   = (const float*)d_in[6];
    const float* Wv   = (const float*)d_in[7];
    const float* bv   = (const float*)d_in[8];
    const float* Wo   = (const float*)d_in[9];
    const float* bo   = (const float*)d_in[10];
    float* out = (float*)d_out;

    // workspace (80 MB), with overlays:
    //   qp 16 MB | kp 16 MB | vp 16 MB | X/aw 16 MB | Wqkvp 12 MB + Wop 4 MB
    unsigned short* qp = (unsigned short*)d_ws;                  // 8M ushorts
    unsigned short* kp = qp + (size_t)8388608;
    unsigned short* vp = kp + (size_t)8388608;
    unsigned short* Xp = vp + (size_t)8388608;                   // packed x
    float*          aw = (float*)Xp;                             // overlay
    unsigned short* Wqkvp = Xp + (size_t)8388608;
    unsigned short* Wop   = Wqkvp + (size_t)6291456;
    unsigned short* Ap2   = qp;                                  // overlay

    pack_swz <<<2048, 256, 0, stream>>>(x, Xp);
    pack_swz3<<<1536, 256, 0, stream>>>(Wq, Wk, Wv, Wqkvp);
    pack_swz <<< 512, 256, 0, stream>>>(Wo, Wop);

    gemm_mfma<<<dim3(24, 16), 512, 0, stream>>>(
        Xp, Wqkvp, 0, bq, bk, bv, qpos, kpos, qp, kp, vp, nullptr, nullptr);

    attn_mfma<<<dim3(SEQ/128, 2*HEADS), 256, 0, stream>>>(qp, kp, vp, aw);

    pack_swz <<<2048, 256, 0, stream>>>(aw, Ap2);

    gemm_mfma<<<dim3(8, 16), 512, 0, stream>>>(
        Ap2, Wop, 1, nullptr, nullptr, nullptr, nullptr, nullptr,
        nullptr, nullptr, nullptr, bo, out);
}